// Round 9
// baseline (215.149 us; speedup 1.0000x reference)
//
#include <hip/hip_runtime.h>
#include <math.h>

// EqualtimeLayer: per (b,post): sort 1024 events by t = spike[b][pre]+delay[pre][post],
// prefix-sum (w, w*t) in sorted order, candidate tmp_k=(theta+cumwt)/cumw valid iff
// cumw>0 && tmp>=t_k && (k==last || tmp<=t_{k+1}); output = min valid tmp.
//
// R9: rotating single-wave solver. Events t<0.6 (~18%, <=256 guarded) are
// bucket-sorted; ONE wave solves the 256-slot window barrier-free (wave-ordered
// LDS: fixup + blocked DPP scan + candidates + exact early-exit vs minExcl)
// while the other waves histogram the NEXT batch (disjoint LDS). 3 barriers per
// batch (was 7). Paired 16-bit bucket counts -> conflict-free b128 count scan.
// Flagged batches (no crossing <0.6 / overflow) re-run block-cooperatively with
// the R8 chunked epoch over [0,2) after the main loop — bit-exact overall.

#define B_TOT 32
#define PRE 1024
#define POST 1024
#define NB 512
#define TPB 256
#define EPT 4
#define BPW 8
#define CHUNK 256
#define BSCALE1 853.33331f   // NB / 0.6  (inclusion window [0, 0.6))
#define BSCALE2 256.0f       // NB / 2.0  (fallback full range)

// ---- DPP helpers (gfx9 encodings) ----
template<int CTRL, int MASK>
__device__ __forceinline__ int dpp_add_i32(int v) {
    return v + __builtin_amdgcn_update_dpp(0, v, CTRL, MASK, 0xf, true);
}
template<int CTRL, int MASK>
__device__ __forceinline__ float dpp_add_f32(float v) {
    int t = __builtin_amdgcn_update_dpp(0, __float_as_int(v), CTRL, MASK, 0xf, true);
    return v + __int_as_float(t);
}
template<int CTRL>
__device__ __forceinline__ float dpp_min_f32(float v) {
    int t = __builtin_amdgcn_update_dpp(__float_as_int(v), __float_as_int(v), CTRL, 0xf, 0xf, false);
    return fminf(v, __int_as_float(t));
}
__device__ __forceinline__ int wave_iscan_i32(int v) {
    v = dpp_add_i32<0x111, 0xf>(v);
    v = dpp_add_i32<0x112, 0xf>(v);
    v = dpp_add_i32<0x114, 0xf>(v);
    v = dpp_add_i32<0x118, 0xf>(v);
    v = dpp_add_i32<0x142, 0xa>(v);
    v = dpp_add_i32<0x143, 0xc>(v);
    return v;
}
__device__ __forceinline__ float wave_iscan_f32(float v) {
    v = dpp_add_f32<0x111, 0xf>(v);
    v = dpp_add_f32<0x112, 0xf>(v);
    v = dpp_add_f32<0x114, 0xf>(v);
    v = dpp_add_f32<0x118, 0xf>(v);
    v = dpp_add_f32<0x142, 0xa>(v);
    v = dpp_add_f32<0x143, 0xc>(v);
    return v;
}
// min valid in lane 0 (only lane 0 consumes it)
__device__ __forceinline__ float wave_min_f32(float v) {
    v = fminf(v, __shfl_down(v, 32));
    v = fminf(v, __shfl_down(v, 16));
    v = dpp_min_f32<0x140>(v);
    v = dpp_min_f32<0x141>(v);
    v = dpp_min_f32<0x4E>(v);
    v = dpp_min_f32<0xB1>(v);
    return v;
}
__device__ __forceinline__ int clampb(int k) {
    return k < 0 ? 0 : (k > NB - 1 ? NB - 1 : k);
}
__device__ __forceinline__ float fmin4(const float* a) {
    return fminf(fminf(a[0], a[1]), fminf(a[2], a[3]));
}
// paired 16-bit histogram add; returns this event's arrival rank in bucket k
__device__ __forceinline__ int hist_add(int* raw, int k) {
    int sh = (k & 1) << 4;
    int old = atomicAdd(&raw[k >> 1], 1 << sh);
    return (old >> sh) & 0xffff;
}

// Redundant (every wave identical) exclusive scan of NB paired-16bit counts.
// One contiguous b128/lane (conflict-free). Wave 0 writes packed (off<<12|cnt)
// into pck (readers must wait for the next barrier). Returns total (uniform).
__device__ __forceinline__ int scan_counts_paired(const int* raw, int* pck,
                                                  int lane, int wid) {
    int4 v = reinterpret_cast<const int4*>(raw)[lane];
    int c[8] = {v.x & 0xffff, v.x >> 16, v.y & 0xffff, v.y >> 16,
                v.z & 0xffff, v.z >> 16, v.w & 0xffff, v.w >> 16};
    int ls[8]; int s = 0;
#pragma unroll
    for (int j = 0; j < 8; ++j) { s += c[j]; ls[j] = s; }
    int x = wave_iscan_i32(s);
    int excl = x - s;
    if (wid == 0) {
        int o[8];
#pragma unroll
        for (int j = 0; j < 8; ++j) o[j] = ((excl + ls[j] - c[j]) << 12) | c[j];
        reinterpret_cast<int4*>(pck)[2 * lane]     = make_int4(o[0], o[1], o[2], o[3]);
        reinterpret_cast<int4*>(pck)[2 * lane + 1] = make_int4(o[4], o[5], o[6], o[7]);
    }
    return __builtin_amdgcn_readlane(x, 63);
}

// Block-cooperative chunked solve (fallback path; R8-proven). Processes
// [cStart,cEnd) in 256-chunks with fixup, exact boundary, scan, candidates,
// early exit. Bucket index clamp((t-t0f)*scale), base offset baseOff.
__device__ __forceinline__ bool run_epoch(
    float* s_t, float* s_w, const int* pck, float* s_fw, float* s_fwt, float* s_red,
    int cStart, int cEnd, int posLo, int posValidEnd,
    float t0f, int baseOff, float tEnd, float theta, float scale,
    int tid, int lane, int wid, float& cumW, float& cumWT, float& mAll)
{
    for (int c0 = cStart; c0 < cEnd; c0 += CHUNK) {
        const int next = c0 + CHUNK;
        const int p = c0 + tid;
        const bool valid = (p >= posLo);

        float e_t = s_t[p], e_w = s_w[p];
        int np = -1;
        if (valid) {
            int k = clampb((int)((e_t - t0f) * scale));
            int pk = pck[k];
            int bas = (pk >> 12) + baseOff, cn = pk & 0xfff;
            if (bas >= c0 && cn > 1) {
                int r = 0;
                for (int q = bas; q < bas + cn; ++q) {
                    float tq = s_t[q];
                    r += ((tq < e_t) || (tq == e_t && q < p)) ? 1 : 0;
                }
                int tgt = bas + r;
                if (tgt != p) np = tgt;
            }
        }
        int np2 = -1; float e2t = 0.f, e2w = 0.f;
        if (tid < 64) {
            int p2 = next + tid;
            if (p2 < cEnd && p2 >= posLo) {
                e2t = s_t[p2]; e2w = s_w[p2];
                int k = clampb((int)((e2t - t0f) * scale));
                int pk = pck[k];
                int bas = (pk >> 12) + baseOff, cn = pk & 0xfff;
                if (bas >= c0 && bas < next && cn > 1) {
                    int r = 0;
                    for (int q = bas; q < bas + cn; ++q) {
                        float tq = s_t[q];
                        r += ((tq < e2t) || (tq == e2t && q < p2)) ? 1 : 0;
                    }
                    int tgt = bas + r;
                    if (tgt != p2) np2 = tgt;
                }
            }
        }
        __syncthreads();
        if (np  >= 0) { s_t[np]  = e_t;  s_w[np]  = e_w; }
        if (np2 >= 0) { s_t[np2] = e2t; s_w[np2] = e2w; }
        __syncthreads();

        float t_next = tEnd;
        if (next < cEnd) {
            float tx = s_t[next];
            int k = clampb((int)((tx - t0f) * scale));
            int pk = pck[k];
            int bas = (pk >> 12) + baseOff, cn = pk & 0xfff;
            t_next = tx;
            if (bas >= next) {
                for (int q = bas; q < bas + cn; ++q) t_next = fminf(t_next, s_t[q]);
            }
        }

        float t_p = s_t[p];
        float w_p = valid ? s_w[p] : 0.f;
        float aw = w_p, awt = w_p * t_p;
        float xw  = wave_iscan_f32(aw);
        float xwt = wave_iscan_f32(awt);
        if (lane == 63) { s_fw[wid] = xw; s_fwt[wid] = xwt; }
        float tn = (p == PRE - 1) ? INFINITY
                 : (tid == TPB - 1) ? t_next : s_t[p + 1];
        __syncthreads();
        float W = cumW, WT = cumWT;
        for (int k2 = 0; k2 < wid; ++k2) { W += s_fw[k2]; WT += s_fwt[k2]; }
        W += xw; WT += xwt;
        cumW  += s_fw[0] + s_fw[1] + s_fw[2] + s_fw[3];
        cumWT += s_fwt[0] + s_fwt[1] + s_fwt[2] + s_fwt[3];

        float mc = INFINITY;
        if (valid && p < posValidEnd && W > 0.f) {
            float tmp = (theta + WT) * __builtin_amdgcn_rcpf(W);
            if (tmp >= t_p && tmp <= tn) mc = tmp;
        }
        mc = wave_min_f32(mc);
        if (lane == 0) s_red[wid] = mc;
        __syncthreads();
        mAll = fminf(mAll,
               fminf(fminf(s_red[0], s_red[1]), fminf(s_red[2], s_red[3])));
        if (mAll <= t_next) return true;
    }
    return false;
}

__global__ __launch_bounds__(TPB, 8) void equaltime_kernel(
    const float* __restrict__ spikes,     // [B][PRE]
    const float* __restrict__ weights,    // [PRE][POST]
    const float* __restrict__ delays,     // [PRE][POST]
    const float* __restrict__ thresholds, // [POST]
    float* __restrict__ out)              // [B][POST]
{
    __shared__ __align__(16) float s_t[PRE];       // 4 KB (full size: overflow-safe)
    __shared__ __align__(16) float s_w[PRE];       // 4 KB
    __shared__ __align__(16) int   s_raw[NB / 2];  // 1 KB paired 16-bit counts
    __shared__ __align__(16) int   s_pck[NB];      // 2 KB packed (off<<12|cnt)
    __shared__ float s_redP[2][4];                 // minExcl partials, dbuf by parity
    __shared__ float s_fw[4], s_fwt[4], s_red[4];  // fallback-only exchange
    __shared__ int   s_flag[BPW];

    const int tid  = threadIdx.x;
    const int lane = tid & 63;
    const int wid  = tid >> 6;

    // XCD-contiguous swizzle for weight/delay L2 locality
    const int bx   = blockIdx.x;
    const int sbx  = (bx & 7) * 512 + (bx >> 3);
    const int post = sbx >> 2;            // 4 WGs per post
    const int b0   = (sbx & 3) * BPW;
    const float theta = thresholds[post];

    float dly[EPT], wgt[EPT];
#pragma unroll
    for (int j = 0; j < EPT; ++j) {
        int pre = tid * EPT + j;
        dly[j] = delays[pre * POST + post];
        wgt[j] = weights[pre * POST + post];
    }

    if (tid < BPW) s_flag[tid] = 0;
    s_raw[tid] = 0;                       // 256 ints, 256 threads
    __syncthreads();

    float tv[EPT]; int bkt[EPT], rnk[EPT];

    // ---- prologue: stage-A for batch 0 (hist -> scan -> scatter) ----
    {
        float4 sp = *reinterpret_cast<const float4*>(spikes + b0 * PRE + tid * EPT);
        tv[0] = sp.x + dly[0]; tv[1] = sp.y + dly[1];
        tv[2] = sp.z + dly[2]; tv[3] = sp.w + dly[3];
        float mloc = INFINITY;
#pragma unroll
        for (int j = 0; j < EPT; ++j) {
            int k = (int)(tv[j] * BSCALE1);
            bkt[j] = k;
            if (k < NB) rnk[j] = hist_add(s_raw, k);
            else        mloc = fminf(mloc, tv[j]);
        }
        mloc = wave_min_f32(mloc);
        if (lane == 0) s_redP[0][wid] = mloc;
    }
    __syncthreads();                                        // B1
    int N_cur = scan_counts_paired(s_raw, s_pck, lane, wid);
    __syncthreads();                                        // B2
    {
        float minE = fmin4(s_redP[0]);
#pragma unroll
        for (int j = 0; j < EPT; ++j) {
            if (bkt[j] < NB) {
                int pos = (s_pck[bkt[j]] >> 12) + rnk[j];
                s_t[pos] = tv[j];
                s_w[pos] = wgt[j];
            }
        }
        int h = N_cur + tid;
        if (h < CHUNK) { s_t[h] = minE; s_w[h] = 0.f; }
        if (wid == 1) reinterpret_cast<int4*>(s_raw)[lane] = make_int4(0, 0, 0, 0);
    }
    __syncthreads();                                        // B3

    // ---- main loop: solve(bi) by wave (bi&3) || stage-A(bi+1) by all ----
    for (int bi = 0; bi < BPW; ++bi) {
        const int b = b0 + bi;

        if (wid == (bi & 3)) {
            // -------- single-wave barrier-free solve of batch bi --------
            float minE = fmin4(s_redP[bi & 1]);
            if (N_cur > CHUNK) {
                if (lane == 0) s_flag[bi] = 1;   // capacity overflow (P~1e-4)
            } else {
                // fixup: exact in-bucket rank, stripes lane+64s
                float gt[4], gw[4]; int np[4];
#pragma unroll
                for (int s = 0; s < 4; ++s) {
                    int p = 64 * s + lane;
                    np[s] = -1;
                    if (p < N_cur) {
                        float et = s_t[p], ew = s_w[p];
                        int k = (int)(et * BSCALE1); k = k < NB - 1 ? k : NB - 1;
                        int pk = s_pck[k];
                        int bas = pk >> 12, cn = pk & 0xfff;
                        if (cn > 1) {
                            int r = 0;
                            for (int q = bas; q < bas + cn; ++q) {
                                float tq = s_t[q];
                                r += ((tq < et) || (tq == et && q < p)) ? 1 : 0;
                            }
                            int tgt = bas + r;
                            if (tgt != p) { np[s] = tgt; gt[s] = et; gw[s] = ew; }
                        }
                    }
                }
#pragma unroll
                for (int s = 0; s < 4; ++s)
                    if (np[s] >= 0) { s_t[np[s]] = gt[s]; s_w[np[s]] = gw[s]; }

                // blocked scan of (w, w*t) over 256 sorted slots (holes w=0)
                float4 t4 = reinterpret_cast<float4*>(s_t)[lane];
                float4 w4 = reinterpret_cast<float4*>(s_w)[lane];
                float st[4] = {t4.x, t4.y, t4.z, t4.w};
                float sw[4] = {w4.x, w4.y, w4.z, w4.w};
                float cw[4], cwt[4];
                float aw = 0.f, awt = 0.f;
#pragma unroll
                for (int j = 0; j < EPT; ++j) {
                    aw += sw[j]; awt += sw[j] * st[j]; cw[j] = aw; cwt[j] = awt;
                }
                float xw  = wave_iscan_f32(aw);
                float xwt = wave_iscan_f32(awt);
                float baseW = xw - aw, baseWT = xwt - awt;
                float tnl = __shfl_down(st[0], 1);  // next lane's first t
                if (lane == 63) tnl = minE;

                float mc = INFINITY;
#pragma unroll
                for (int j = 0; j < EPT; ++j) {
                    int p = 4 * lane + j;
                    float W  = baseW  + cw[j];
                    float WT = baseWT + cwt[j];
                    float tn = (j < 3) ? st[j + 1] : tnl;
                    if (p < N_cur && W > 0.f) {
                        float tmp = (theta + WT) * __builtin_amdgcn_rcpf(W);
                        if (tmp >= st[j] && tmp <= tn) mc = fminf(mc, tmp);
                    }
                }
                mc = wave_min_f32(mc);
                if (lane == 0) {
                    if (mc <= minE) out[b * POST + post] = mc; // exact early exit
                    else            s_flag[bi] = 1;            // needs tail (rare)
                }
            }
        }

        // -------- stage-A for batch bi+1 (all waves; solver after solving) ---
        int N_nxt = 0;
        if (bi + 1 < BPW) {
            const int b2 = b0 + bi + 1;
            float4 sp = *reinterpret_cast<const float4*>(spikes + b2 * PRE + tid * EPT);
            tv[0] = sp.x + dly[0]; tv[1] = sp.y + dly[1];
            tv[2] = sp.z + dly[2]; tv[3] = sp.w + dly[3];
            float mloc = INFINITY;
#pragma unroll
            for (int j = 0; j < EPT; ++j) {
                int k = (int)(tv[j] * BSCALE1);
                bkt[j] = k;
                if (k < NB) rnk[j] = hist_add(s_raw, k);
                else        mloc = fminf(mloc, tv[j]);
            }
            mloc = wave_min_f32(mloc);
            if (lane == 0) s_redP[(bi + 1) & 1][wid] = mloc;
        }
        __syncthreads();                                    // B1'
        if (bi + 1 < BPW) {
            N_nxt = scan_counts_paired(s_raw, s_pck, lane, wid);
            __syncthreads();                                // B2'
            float minE2 = fmin4(s_redP[(bi + 1) & 1]);
#pragma unroll
            for (int j = 0; j < EPT; ++j) {
                if (bkt[j] < NB) {
                    int pos = (s_pck[bkt[j]] >> 12) + rnk[j];
                    s_t[pos] = tv[j];
                    s_w[pos] = wgt[j];
                }
            }
            int h = N_nxt + tid;
            if (h < CHUNK) { s_t[h] = minE2; s_w[h] = 0.f; }
            if (wid == 1) reinterpret_cast<int4*>(s_raw)[lane] = make_int4(0, 0, 0, 0);
            __syncthreads();                                // B3'
        }
        N_cur = N_nxt;
    }

    // ---- fallback: block-cooperative exact re-solve of flagged batches ----
    for (int fb = 0; fb < BPW; ++fb) {
        if (s_flag[fb] == 0) continue;    // uniform branch (all read same LDS)
        const int b = b0 + fb;
        s_raw[tid] = 0;
        __syncthreads();
        float4 sp = *reinterpret_cast<const float4*>(spikes + b * PRE + tid * EPT);
        float tf[4] = {sp.x + dly[0], sp.y + dly[1], sp.z + dly[2], sp.w + dly[3]};
        int bk[4], rk[4];
#pragma unroll
        for (int j = 0; j < EPT; ++j) {
            int k = (int)(tf[j] * BSCALE2); k = k < NB - 1 ? k : NB - 1;
            bk[j] = k;
            rk[j] = hist_add(s_raw, k);
        }
        __syncthreads();
        (void)scan_counts_paired(s_raw, s_pck, lane, wid);
        __syncthreads();
#pragma unroll
        for (int j = 0; j < EPT; ++j) {
            int pos = (s_pck[bk[j]] >> 12) + rk[j];
            s_t[pos] = tf[j];
            s_w[pos] = wgt[j];
        }
        __syncthreads();
        float cumW = 0.f, cumWT = 0.f, mAll = INFINITY;
        run_epoch(s_t, s_w, s_pck, s_fw, s_fwt, s_red,
                  0, PRE, 0, PRE, 0.f, 0, INFINITY, theta, BSCALE2,
                  tid, lane, wid, cumW, cumWT, mAll);
        if (tid == 0) out[b * POST + post] = mAll;
        __syncthreads();
    }
}

extern "C" void kernel_launch(void* const* d_in, const int* in_sizes, int n_in,
                              void* d_out, int out_size, void* d_ws, size_t ws_size,
                              hipStream_t stream) {
    const float* spikes     = (const float*)d_in[0]; // [32,1024]
    const float* weights    = (const float*)d_in[1]; // [1024,1024]
    const float* delays     = (const float*)d_in[2]; // [1024,1024]
    const float* thresholds = (const float*)d_in[3]; // [1024]
    float* outp = (float*)d_out;                     // [32,1024]

    dim3 grid(POST * (B_TOT / BPW)); // 4096 workgroups
    dim3 block(TPB);
    equaltime_kernel<<<grid, block, 0, stream>>>(spikes, weights, delays, thresholds, outp);
}

// Round 10
// 148.019 us; speedup vs baseline: 1.4535x; 1.4535x over previous
//
#include <hip/hip_runtime.h>
#include <math.h>

// EqualtimeLayer: per (b,post): sort 1024 events by t = spike[b][pre]+delay[pre][post],
// prefix-sum (w, w*t) in sorted order, candidate tmp_k=(theta+cumwt)/cumw valid iff
// cumw>0 && tmp>=t_k && (k==last || tmp<=t_{k+1}); output = min valid tmp.
//
// R10: paired batches. Events t<0.6 (~185, <=256 guarded) bucket-sorted into two
// 256-slot windows (batch A, batch B) with two count buffers; one barrier set
// serves both batches -> 3.5 barriers/batch (R8: 7). Wave0/wave1 scan counts
// non-redundantly (paired 16-bit, conflict-free b128). Single-chunk solve per
// window: boundary = exact min excluded time; exact early exit. Flagged batches
// (no crossing <0.6 / overflow) re-solved by proven full-range chunked epilogue.
// Per-thread arrays die at scatter -> no scratch spill (R9's failure mode).

#define B_TOT 32
#define PRE 1024
#define POST 1024
#define NB 512
#define TPB 256
#define EPT 4
#define BPW 8
#define CHUNK 256
#define WINB 256
#define BSCALE1 853.33331f   // NB / 0.6  (inclusion window [0,0.6))
#define BSCALE2 256.0f       // NB / 2.0  (fallback full range)

// ---- DPP helpers (gfx9 encodings) ----
template<int CTRL, int MASK>
__device__ __forceinline__ int dpp_add_i32(int v) {
    return v + __builtin_amdgcn_update_dpp(0, v, CTRL, MASK, 0xf, true);
}
template<int CTRL, int MASK>
__device__ __forceinline__ float dpp_add_f32(float v) {
    int t = __builtin_amdgcn_update_dpp(0, __float_as_int(v), CTRL, MASK, 0xf, true);
    return v + __int_as_float(t);
}
template<int CTRL>
__device__ __forceinline__ float dpp_min_f32(float v) {
    int t = __builtin_amdgcn_update_dpp(__float_as_int(v), __float_as_int(v), CTRL, 0xf, 0xf, false);
    return fminf(v, __int_as_float(t));
}
__device__ __forceinline__ int wave_iscan_i32(int v) {
    v = dpp_add_i32<0x111, 0xf>(v);
    v = dpp_add_i32<0x112, 0xf>(v);
    v = dpp_add_i32<0x114, 0xf>(v);
    v = dpp_add_i32<0x118, 0xf>(v);
    v = dpp_add_i32<0x142, 0xa>(v);
    v = dpp_add_i32<0x143, 0xc>(v);
    return v;
}
__device__ __forceinline__ float wave_iscan_f32(float v) {
    v = dpp_add_f32<0x111, 0xf>(v);
    v = dpp_add_f32<0x112, 0xf>(v);
    v = dpp_add_f32<0x114, 0xf>(v);
    v = dpp_add_f32<0x118, 0xf>(v);
    v = dpp_add_f32<0x142, 0xa>(v);
    v = dpp_add_f32<0x143, 0xc>(v);
    return v;
}
// min valid in lane 0
__device__ __forceinline__ float wave_min_f32(float v) {
    v = fminf(v, __shfl_down(v, 32));
    v = fminf(v, __shfl_down(v, 16));
    v = dpp_min_f32<0x140>(v);
    v = dpp_min_f32<0x141>(v);
    v = dpp_min_f32<0x4E>(v);
    v = dpp_min_f32<0xB1>(v);
    return v;
}
__device__ __forceinline__ int clampb(int k) {
    return k < 0 ? 0 : (k > NB - 1 ? NB - 1 : k);
}
__device__ __forceinline__ float fmin4(const float* a) {
    return fminf(fminf(a[0], a[1]), fminf(a[2], a[3]));
}
// paired 16-bit histogram add; returns arrival rank in bucket k
__device__ __forceinline__ int hist_add(int* raw, int k) {
    int sh = (k & 1) << 4;
    int old = atomicAdd(&raw[k >> 1], 1 << sh);
    return (old >> sh) & 0xffff;
}

// Single-wave exclusive scan of NB paired-16bit counts; writes packed
// (off<<12|cnt) into pck. One conflict-free b128/lane. Returns total.
__device__ __forceinline__ int scan_counts_wave(const int* raw, int* pck, int lane) {
    int4 v = reinterpret_cast<const int4*>(raw)[lane];
    int c[8] = {v.x & 0xffff, v.x >> 16, v.y & 0xffff, v.y >> 16,
                v.z & 0xffff, v.z >> 16, v.w & 0xffff, v.w >> 16};
    int ls[8]; int s = 0;
#pragma unroll
    for (int j = 0; j < 8; ++j) { s += c[j]; ls[j] = s; }
    int x = wave_iscan_i32(s);
    int excl = x - s;
    int o[8];
#pragma unroll
    for (int j = 0; j < 8; ++j) o[j] = ((excl + ls[j] - c[j]) << 12) | c[j];
    reinterpret_cast<int4*>(pck)[2 * lane]     = make_int4(o[0], o[1], o[2], o[3]);
    reinterpret_cast<int4*>(pck)[2 * lane + 1] = make_int4(o[4], o[5], o[6], o[7]);
    return __builtin_amdgcn_readlane(x, 63);
}

// Block-cooperative chunked solve (R8-proven; fallback only).
__device__ __forceinline__ bool run_epoch(
    float* s_t, float* s_w, const int* pck, float* s_fw, float* s_fwt, float* s_red,
    int cStart, int cEnd, int posLo, int posValidEnd,
    float t0f, int baseOff, float tEnd, float theta, float scale,
    int tid, int lane, int wid, float& cumW, float& cumWT, float& mAll)
{
    for (int c0 = cStart; c0 < cEnd; c0 += CHUNK) {
        const int next = c0 + CHUNK;
        const int p = c0 + tid;
        const bool valid = (p >= posLo);

        float e_t = s_t[p], e_w = s_w[p];
        int np = -1;
        if (valid) {
            int k = clampb((int)((e_t - t0f) * scale));
            int pk = pck[k];
            int bas = (pk >> 12) + baseOff, cn = pk & 0xfff;
            if (bas >= c0 && cn > 1) {
                int r = 0;
                for (int q = bas; q < bas + cn; ++q) {
                    float tq = s_t[q];
                    r += ((tq < e_t) || (tq == e_t && q < p)) ? 1 : 0;
                }
                int tgt = bas + r;
                if (tgt != p) np = tgt;
            }
        }
        int np2 = -1; float e2t = 0.f, e2w = 0.f;
        if (tid < 64) {
            int p2 = next + tid;
            if (p2 < cEnd && p2 >= posLo) {
                e2t = s_t[p2]; e2w = s_w[p2];
                int k = clampb((int)((e2t - t0f) * scale));
                int pk = pck[k];
                int bas = (pk >> 12) + baseOff, cn = pk & 0xfff;
                if (bas >= c0 && bas < next && cn > 1) {
                    int r = 0;
                    for (int q = bas; q < bas + cn; ++q) {
                        float tq = s_t[q];
                        r += ((tq < e2t) || (tq == e2t && q < p2)) ? 1 : 0;
                    }
                    int tgt = bas + r;
                    if (tgt != p2) np2 = tgt;
                }
            }
        }
        __syncthreads();
        if (np  >= 0) { s_t[np]  = e_t;  s_w[np]  = e_w; }
        if (np2 >= 0) { s_t[np2] = e2t; s_w[np2] = e2w; }
        __syncthreads();

        float t_next = tEnd;
        if (next < cEnd) {
            float tx = s_t[next];
            int k = clampb((int)((tx - t0f) * scale));
            int pk = pck[k];
            int bas = (pk >> 12) + baseOff, cn = pk & 0xfff;
            t_next = tx;
            if (bas >= next) {
                for (int q = bas; q < bas + cn; ++q) t_next = fminf(t_next, s_t[q]);
            }
        }

        float t_p = s_t[p];
        float w_p = valid ? s_w[p] : 0.f;
        float aw = w_p, awt = w_p * t_p;
        float xw  = wave_iscan_f32(aw);
        float xwt = wave_iscan_f32(awt);
        if (lane == 63) { s_fw[wid] = xw; s_fwt[wid] = xwt; }
        float tn = (p == PRE - 1) ? INFINITY
                 : (tid == TPB - 1) ? t_next : s_t[p + 1];
        __syncthreads();
        float W = cumW, WT = cumWT;
        for (int k2 = 0; k2 < wid; ++k2) { W += s_fw[k2]; WT += s_fwt[k2]; }
        W += xw; WT += xwt;
        cumW  += s_fw[0] + s_fw[1] + s_fw[2] + s_fw[3];
        cumWT += s_fwt[0] + s_fwt[1] + s_fwt[2] + s_fwt[3];

        float mc = INFINITY;
        if (valid && p < posValidEnd && W > 0.f) {
            float tmp = (theta + WT) * __builtin_amdgcn_rcpf(W);
            if (tmp >= t_p && tmp <= tn) mc = tmp;
        }
        mc = wave_min_f32(mc);
        if (lane == 0) s_red[wid] = mc;
        __syncthreads();
        mAll = fminf(mAll,
               fminf(fminf(s_red[0], s_red[1]), fminf(s_red[2], s_red[3])));
        if (mAll <= t_next) return true;
    }
    return false;
}

__global__ __launch_bounds__(TPB, 8) void equaltime_kernel(
    const float* __restrict__ spikes,     // [B][PRE]
    const float* __restrict__ weights,    // [PRE][POST]
    const float* __restrict__ delays,     // [PRE][POST]
    const float* __restrict__ thresholds, // [POST]
    float* __restrict__ out)              // [B][POST]
{
    __shared__ __align__(16) float s_t[PRE];      // 4 KB (windows A/B + fallback)
    __shared__ __align__(16) float s_w[PRE];      // 4 KB
    __shared__ __align__(16) int   s_rawA[NB/2];  // 1 KB paired 16-bit counts
    __shared__ __align__(16) int   s_rawB[NB/2];  // 1 KB
    __shared__ __align__(16) int   s_pckA[NB];    // 2 KB packed (off<<12|cnt)
    __shared__ __align__(16) int   s_pckB[NB];    // 2 KB
    __shared__ float s_mA[4], s_mB[4];            // minExcl partials
    __shared__ int   s_N[2];
    __shared__ float s_fw[2][4], s_fwt[2][4], s_red[2][4];
    __shared__ int   s_flag[BPW];

    const int tid  = threadIdx.x;
    const int lane = tid & 63;
    const int wid  = tid >> 6;

    // XCD-contiguous swizzle for weight/delay L2 locality
    const int bx   = blockIdx.x;
    const int sbx  = (bx & 7) * 512 + (bx >> 3);
    const int post = sbx >> 2;            // 4 WGs per post
    const int b0   = (sbx & 3) * BPW;
    const float theta = thresholds[post];

    float dly[EPT], wgt[EPT];
#pragma unroll
    for (int j = 0; j < EPT; ++j) {
        int pre = tid * EPT + j;
        dly[j] = delays[pre * POST + post];
        wgt[j] = weights[pre * POST + post];
    }

    if (tid < BPW) s_flag[tid] = 0;
    s_rawA[tid] = 0;                      // 256 ints each
    s_rawB[tid] = 0;
    __syncthreads();

    for (int pr = 0; pr < BPW / 2; ++pr) {
        const int bA = b0 + 2 * pr, bB = bA + 1;

        // ---- hist both batches ----
        float4 spA = *reinterpret_cast<const float4*>(spikes + bA * PRE + tid * EPT);
        float4 spB = *reinterpret_cast<const float4*>(spikes + bB * PRE + tid * EPT);
        float tvA[EPT] = {spA.x + dly[0], spA.y + dly[1], spA.z + dly[2], spA.w + dly[3]};
        float tvB[EPT] = {spB.x + dly[0], spB.y + dly[1], spB.z + dly[2], spB.w + dly[3]};
        int rnkA[EPT], rnkB[EPT];
        float mlA = INFINITY, mlB = INFINITY;
#pragma unroll
        for (int j = 0; j < EPT; ++j) {
            int k = (int)(tvA[j] * BSCALE1);
            if (k < NB) rnkA[j] = hist_add(s_rawA, k);
            else        mlA = fminf(mlA, tvA[j]);
        }
#pragma unroll
        for (int j = 0; j < EPT; ++j) {
            int k = (int)(tvB[j] * BSCALE1);
            if (k < NB) rnkB[j] = hist_add(s_rawB, k);
            else        mlB = fminf(mlB, tvB[j]);
        }
        mlA = wave_min_f32(mlA);
        mlB = wave_min_f32(mlB);
        if (lane == 0) { s_mA[wid] = mlA; s_mB[wid] = mlB; }
        __syncthreads();                                    // B1: counts final

        // ---- scans (non-redundant: wave0->A, wave1->B) ----
        if (wid == 0) {
            int n = scan_counts_wave(s_rawA, s_pckA, lane);
            if (lane == 0) s_N[0] = n;
        } else if (wid == 1) {
            int n = scan_counts_wave(s_rawB, s_pckB, lane);
            if (lane == 0) s_N[1] = n;
        }
        __syncthreads();                                    // B2: pck+N+minE visible

        const int   NA  = s_N[0], NBv = s_N[1];
        const float mEA = fmin4(s_mA), mEB = fmin4(s_mB);
        const bool  okA = (NA <= CHUNK), okB = (NBv <= CHUNK);

        // ---- scatter both windows + hole pad; wid2/3 zero raws ----
        if (okA) {
#pragma unroll
            for (int j = 0; j < EPT; ++j) {
                int k = (int)(tvA[j] * BSCALE1);
                if (k < NB) {
                    int pos = (s_pckA[k] >> 12) + rnkA[j];
                    s_t[pos] = tvA[j];
                    s_w[pos] = wgt[j];
                }
            }
            int h = NA + tid;
            if (h < CHUNK) { s_t[h] = mEA; s_w[h] = 0.f; }
        }
        if (okB) {
#pragma unroll
            for (int j = 0; j < EPT; ++j) {
                int k = (int)(tvB[j] * BSCALE1);
                if (k < NB) {
                    int pos = WINB + (s_pckB[k] >> 12) + rnkB[j];
                    s_t[pos] = tvB[j];
                    s_w[pos] = wgt[j];
                }
            }
            int h = NBv + tid;
            if (h < CHUNK) { s_t[WINB + h] = mEB; s_w[WINB + h] = 0.f; }
        }
        if (wid == 2) reinterpret_cast<int4*>(s_rawA)[lane] = make_int4(0, 0, 0, 0);
        if (wid == 3) reinterpret_cast<int4*>(s_rawB)[lane] = make_int4(0, 0, 0, 0);
        __syncthreads();                                    // B3: scatter visible

        // ---- fixup gather, both windows (1 position each per thread) ----
        int npA = -1, npB = -1;
        float gtA = 0.f, gwA = 0.f, gtB = 0.f, gwB = 0.f;
        if (okA && tid < NA) {
            float et = s_t[tid], ew = s_w[tid];
            int k = (int)(et * BSCALE1);                    // < NB by construction
            int pk = s_pckA[k];
            int bas = pk >> 12, cn = pk & 0xfff;
            if (cn > 1) {
                int r = 0;
                for (int q = bas; q < bas + cn; ++q) {
                    float tq = s_t[q];
                    r += ((tq < et) || (tq == et && q < tid)) ? 1 : 0;
                }
                int tgt = bas + r;
                if (tgt != tid) { npA = tgt; gtA = et; gwA = ew; }
            }
        }
        if (okB && tid < NBv) {
            int p2 = WINB + tid;
            float et = s_t[p2], ew = s_w[p2];
            int k = (int)(et * BSCALE1);
            int pk = s_pckB[k];
            int bas = WINB + (pk >> 12), cn = pk & 0xfff;
            if (cn > 1) {
                int r = 0;
                for (int q = bas; q < bas + cn; ++q) {
                    float tq = s_t[q];
                    r += ((tq < et) || (tq == et && q < p2)) ? 1 : 0;
                }
                int tgt = bas + r;
                if (tgt != p2) { npB = tgt; gtB = et; gwB = ew; }
            }
        }
        __syncthreads();                                    // Bb: gathers done
        if (npA >= 0) { s_t[npA] = gtA; s_w[npA] = gwA; }
        if (npB >= 0) { s_t[npB] = gtB; s_w[npB] = gwB; }
        __syncthreads();                                    // Bc: fixup visible

        // ---- scans of (w, w*t), both windows ----
        float tA = s_t[tid],        wA = okA ? s_w[tid] : 0.f;
        float tB = s_t[WINB + tid], wB = okB ? s_w[WINB + tid] : 0.f;
        float xwA  = wave_iscan_f32(wA);
        float xwtA = wave_iscan_f32(wA * tA);
        float xwB  = wave_iscan_f32(wB);
        float xwtB = wave_iscan_f32(wB * tB);
        if (lane == 63) {
            s_fw[0][wid] = xwA; s_fwt[0][wid] = xwtA;
            s_fw[1][wid] = xwB; s_fwt[1][wid] = xwtB;
        }
        float tnA = (tid == TPB - 1) ? mEA : s_t[tid + 1];
        float tnB = (tid == TPB - 1) ? mEB : s_t[WINB + tid + 1];
        __syncthreads();                                    // Bd: partials visible
        float WA = 0.f, WTA = 0.f, WB = 0.f, WTB = 0.f;
        for (int k2 = 0; k2 < wid; ++k2) {
            WA += s_fw[0][k2]; WTA += s_fwt[0][k2];
            WB += s_fw[1][k2]; WTB += s_fwt[1][k2];
        }
        WA += xwA; WTA += xwtA;
        WB += xwB; WTB += xwtB;

        // ---- candidates + block mins ----
        float mcA = INFINITY, mcB = INFINITY;
        if (okA && tid < NA && WA > 0.f) {
            float tmp = (theta + WTA) * __builtin_amdgcn_rcpf(WA);
            if (tmp >= tA && tmp <= tnA) mcA = tmp;
        }
        if (okB && tid < NBv && WB > 0.f) {
            float tmp = (theta + WTB) * __builtin_amdgcn_rcpf(WB);
            if (tmp >= tB && tmp <= tnB) mcB = tmp;
        }
        mcA = wave_min_f32(mcA);
        mcB = wave_min_f32(mcB);
        if (lane == 0) { s_red[0][wid] = mcA; s_red[1][wid] = mcB; }
        __syncthreads();                                    // Be: mins visible
        float mA = fmin4(s_red[0]), mB = fmin4(s_red[1]);
        if (tid == 0) {
            if (okA && mA <= mEA) out[bA * POST + post] = mA;
            else                  s_flag[2 * pr] = 1;
            if (okB && mB <= mEB) out[bB * POST + post] = mB;
            else                  s_flag[2 * pr + 1] = 1;
        }
        // next pair's hist atomics (into zeroed raws) are safe without a
        // barrier: raws were zeroed pre-B3, last read pre-B2.
    }
    __syncthreads();   // flags visible

    // ---- fallback: block-cooperative exact re-solve of flagged batches ----
    for (int fb = 0; fb < BPW; ++fb) {
        if (s_flag[fb] == 0) continue;    // uniform (all threads read same LDS)
        const int b = b0 + fb;
        s_rawA[tid] = 0;
        __syncthreads();
        float4 sp = *reinterpret_cast<const float4*>(spikes + b * PRE + tid * EPT);
        float tf[EPT] = {sp.x + dly[0], sp.y + dly[1], sp.z + dly[2], sp.w + dly[3]};
        int bk[EPT], rk[EPT];
#pragma unroll
        for (int j = 0; j < EPT; ++j) {
            int k = (int)(tf[j] * BSCALE2); k = k < NB - 1 ? k : NB - 1;
            bk[j] = k;
            rk[j] = hist_add(s_rawA, k);
        }
        __syncthreads();
        if (wid == 0) (void)scan_counts_wave(s_rawA, s_pckA, lane);
        __syncthreads();
#pragma unroll
        for (int j = 0; j < EPT; ++j) {
            int pos = (s_pckA[bk[j]] >> 12) + rk[j];
            s_t[pos] = tf[j];
            s_w[pos] = wgt[j];
        }
        __syncthreads();
        float cumW = 0.f, cumWT = 0.f, mAll = INFINITY;
        run_epoch(s_t, s_w, s_pckA, s_fw[0], s_fwt[0], s_red[0],
                  0, PRE, 0, PRE, 0.f, 0, INFINITY, theta, BSCALE2,
                  tid, lane, wid, cumW, cumWT, mAll);
        if (tid == 0) out[b * POST + post] = mAll;
        __syncthreads();
    }
}

extern "C" void kernel_launch(void* const* d_in, const int* in_sizes, int n_in,
                              void* d_out, int out_size, void* d_ws, size_t ws_size,
                              hipStream_t stream) {
    const float* spikes     = (const float*)d_in[0]; // [32,1024]
    const float* weights    = (const float*)d_in[1]; // [1024,1024]
    const float* delays     = (const float*)d_in[2]; // [1024,1024]
    const float* thresholds = (const float*)d_in[3]; // [1024]
    float* outp = (float*)d_out;                     // [32,1024]

    dim3 grid(POST * (B_TOT / BPW)); // 4096 workgroups
    dim3 block(TPB);
    equaltime_kernel<<<grid, block, 0, stream>>>(spikes, weights, delays, thresholds, outp);
}

// Round 11
// 147.024 us; speedup vs baseline: 1.4634x; 1.0068x over previous
//
#include <hip/hip_runtime.h>
#include <math.h>

// EqualtimeLayer: per (b,post): sort 1024 events by t = spike[b][pre]+delay[pre][post],
// prefix-sum (w, w*t) in sorted order, candidate tmp_k=(theta+cumwt)/cumw valid iff
// cumw>0 && tmp>=t_k && (k==last || tmp<=t_{k+1}); output = min valid tmp.
//
// R11 = R8 skeleton (proven 79us, spill-free) + paired 16-bit counts:
//  - histogram into s_raw[256] (two 16-bit buckets per int, atomic 1<<16*parity)
//  - redundant per-wave count scan reads ONE contiguous b128/lane (conflict-free;
//    R8's stride-32B scan reads caused ~2.2e6 extra conflict cycles)
//  - fallback = full-range re-solve from scratch (512 buckets over [0,2), lam=2)
// Only events t < 0.625 (~20%) are bucketed/sorted; the rest contribute their
// exact min time (epoch-0 boundary). Crossing t*~0.49 => epoch 0 is one
// 256-chunk with exact early exit. 7 barriers/batch common path.

#define B_TOT 32
#define PRE 1024
#define POST 1024
#define NB 512
#define TPB 256
#define EPT 4
#define BPW 8
#define CHUNK 256
#define TCUTF 0.625f
#define BSCALE1 819.2f     // 512 buckets over [0, 0.625)
#define BSCALE2 256.0f     // 512 buckets over [0, 2)   (fallback)

// ---- DPP helpers (gfx9 encodings) ----
template<int CTRL, int MASK>
__device__ __forceinline__ int dpp_add_i32(int v) {
    return v + __builtin_amdgcn_update_dpp(0, v, CTRL, MASK, 0xf, true);
}
template<int CTRL, int MASK>
__device__ __forceinline__ float dpp_add_f32(float v) {
    int t = __builtin_amdgcn_update_dpp(0, __float_as_int(v), CTRL, MASK, 0xf, true);
    return v + __int_as_float(t);
}
template<int CTRL>
__device__ __forceinline__ float dpp_min_f32(float v) {
    int t = __builtin_amdgcn_update_dpp(__float_as_int(v), __float_as_int(v), CTRL, 0xf, 0xf, false);
    return fminf(v, __int_as_float(t));
}
__device__ __forceinline__ int wave_iscan_i32(int v) {
    v = dpp_add_i32<0x111, 0xf>(v);
    v = dpp_add_i32<0x112, 0xf>(v);
    v = dpp_add_i32<0x114, 0xf>(v);
    v = dpp_add_i32<0x118, 0xf>(v);
    v = dpp_add_i32<0x142, 0xa>(v);
    v = dpp_add_i32<0x143, 0xc>(v);
    return v;
}
__device__ __forceinline__ float wave_iscan_f32(float v) {
    v = dpp_add_f32<0x111, 0xf>(v);
    v = dpp_add_f32<0x112, 0xf>(v);
    v = dpp_add_f32<0x114, 0xf>(v);
    v = dpp_add_f32<0x118, 0xf>(v);
    v = dpp_add_f32<0x142, 0xa>(v);
    v = dpp_add_f32<0x143, 0xc>(v);
    return v;
}
__device__ __forceinline__ float wave_min_f32(float v) {
    v = fminf(v, __shfl_down(v, 32));
    v = fminf(v, __shfl_down(v, 16));
    v = dpp_min_f32<0x140>(v);
    v = dpp_min_f32<0x141>(v);
    v = dpp_min_f32<0x4E>(v);
    v = dpp_min_f32<0xB1>(v);
    return v;
}
__device__ __forceinline__ int clampb(int k) {
    return k < 0 ? 0 : (k > NB - 1 ? NB - 1 : k);
}
// paired 16-bit histogram add; returns arrival rank in bucket k
__device__ __forceinline__ int hist_add(int* raw, int k) {
    int sh = (k & 1) << 4;
    int old = atomicAdd(&raw[k >> 1], 1 << sh);
    return (old >> sh) & 0xffff;
}

// Redundant (every wave identical) exclusive scan of NB paired-16bit counts.
// One contiguous b128/lane (conflict-free). Wave 0 writes packed (off<<12|cnt)
// into pck (readers wait for next barrier). Returns total (uniform).
__device__ __forceinline__ int scan_counts(const int* raw, int* pck, int lane, int wid) {
    int4 v = reinterpret_cast<const int4*>(raw)[lane];
    int c[8] = {v.x & 0xffff, (v.x >> 16) & 0xffff, v.y & 0xffff, (v.y >> 16) & 0xffff,
                v.z & 0xffff, (v.z >> 16) & 0xffff, v.w & 0xffff, (v.w >> 16) & 0xffff};
    int ls[8]; int s = 0;
#pragma unroll
    for (int j = 0; j < 8; ++j) { s += c[j]; ls[j] = s; }
    int x = wave_iscan_i32(s);
    int excl = x - s;
    if (wid == 0) {
        int o[8];
#pragma unroll
        for (int j = 0; j < 8; ++j) o[j] = ((excl + ls[j] - c[j]) << 12) | c[j];
        reinterpret_cast<int4*>(pck)[2 * lane]     = make_int4(o[0], o[1], o[2], o[3]);
        reinterpret_cast<int4*>(pck)[2 * lane + 1] = make_int4(o[4], o[5], o[6], o[7]);
    }
    return __builtin_amdgcn_readlane(x, 63);
}

// Block-cooperative chunked solve (R8-proven). Bucket clamp((t-t0f)*scale).
__device__ __forceinline__ bool run_epoch(
    float* s_t, float* s_w, const int* pck, float* s_fw, float* s_fwt, float* s_red,
    int cStart, int cEnd, int posLo, int posValidEnd,
    float t0f, int baseOff, float tEnd, float theta, float scale,
    int tid, int lane, int wid, float& cumW, float& cumWT, float& mAll)
{
    for (int c0 = cStart; c0 < cEnd; c0 += CHUNK) {
        const int next = c0 + CHUNK;
        const int p = c0 + tid;
        const bool valid = (p >= posLo);

        float e_t = s_t[p], e_w = s_w[p];
        int np = -1;
        if (valid) {
            int k = clampb((int)((e_t - t0f) * scale));
            int pk = pck[k];
            int bas = (pk >> 12) + baseOff, cn = pk & 0xfff;
            if (bas >= c0 && cn > 1) {
                int r = 0;
                for (int q = bas; q < bas + cn; ++q) {
                    float tq = s_t[q];
                    r += ((tq < e_t) || (tq == e_t && q < p)) ? 1 : 0;
                }
                int tgt = bas + r;
                if (tgt != p) np = tgt;
            }
        }
        int np2 = -1; float e2t = 0.f, e2w = 0.f;
        if (tid < 64) {
            int p2 = next + tid;
            if (p2 < cEnd && p2 >= posLo) {
                e2t = s_t[p2]; e2w = s_w[p2];
                int k = clampb((int)((e2t - t0f) * scale));
                int pk = pck[k];
                int bas = (pk >> 12) + baseOff, cn = pk & 0xfff;
                if (bas >= c0 && bas < next && cn > 1) {
                    int r = 0;
                    for (int q = bas; q < bas + cn; ++q) {
                        float tq = s_t[q];
                        r += ((tq < e2t) || (tq == e2t && q < p2)) ? 1 : 0;
                    }
                    int tgt = bas + r;
                    if (tgt != p2) np2 = tgt;
                }
            }
        }
        __syncthreads();                                   // gathers done
        if (np  >= 0) { s_t[np]  = e_t;  s_w[np]  = e_w; }
        if (np2 >= 0) { s_t[np2] = e2t; s_w[np2] = e2w; }
        __syncthreads();                                   // fixup visible

        float t_next = tEnd;
        if (next < cEnd) {
            float tx = s_t[next];
            int k = clampb((int)((tx - t0f) * scale));
            int pk = pck[k];
            int bas = (pk >> 12) + baseOff, cn = pk & 0xfff;
            t_next = tx;
            if (bas >= next) {
                for (int q = bas; q < bas + cn; ++q) t_next = fminf(t_next, s_t[q]);
            }
        }

        float t_p = s_t[p];
        float w_p = valid ? s_w[p] : 0.f;
        float aw = w_p, awt = w_p * t_p;
        float xw  = wave_iscan_f32(aw);
        float xwt = wave_iscan_f32(awt);
        if (lane == 63) { s_fw[wid] = xw; s_fwt[wid] = xwt; }
        float tn = (p == PRE - 1) ? INFINITY
                 : (tid == TPB - 1) ? t_next : s_t[p + 1];
        __syncthreads();                                   // partials visible
        float W = cumW, WT = cumWT;
        for (int k2 = 0; k2 < wid; ++k2) { W += s_fw[k2]; WT += s_fwt[k2]; }
        W += xw; WT += xwt;
        cumW  += s_fw[0] + s_fw[1] + s_fw[2] + s_fw[3];
        cumWT += s_fwt[0] + s_fwt[1] + s_fwt[2] + s_fwt[3];

        float mc = INFINITY;
        if (valid && p < posValidEnd && W > 0.f) {
            float tmp = (theta + WT) * __builtin_amdgcn_rcpf(W);
            if (tmp >= t_p && tmp <= tn) mc = tmp;
        }
        mc = wave_min_f32(mc);
        if (lane == 0) s_red[wid] = mc;
        __syncthreads();                                   // mins visible
        mAll = fminf(mAll,
               fminf(fminf(s_red[0], s_red[1]), fminf(s_red[2], s_red[3])));
        if (mAll <= t_next) return true;
    }
    return false;
}

__global__ __launch_bounds__(TPB, 8) void equaltime_kernel(
    const float* __restrict__ spikes,     // [B][PRE]
    const float* __restrict__ weights,    // [PRE][POST]
    const float* __restrict__ delays,     // [PRE][POST]
    const float* __restrict__ thresholds, // [POST]
    float* __restrict__ out)              // [B][POST]
{
    __shared__ __align__(16) float s_t[PRE];      // 4 KB
    __shared__ __align__(16) float s_w[PRE];      // 4 KB
    __shared__ __align__(16) int   s_raw[NB/2];   // 1 KB paired 16-bit counts
    __shared__ __align__(16) int   s_pck[NB];     // 2 KB packed (off<<12|cnt)
    __shared__ float s_fw[4], s_fwt[4];
    __shared__ float s_red[4];

    const int tid  = threadIdx.x;
    const int lane = tid & 63;
    const int wid  = tid >> 6;

    // XCD-contiguous swizzle for weight/delay L2 locality
    const int bx   = blockIdx.x;
    const int sbx  = (bx & 7) * 512 + (bx >> 3);
    const int post = sbx >> 2;            // 4 WGs per post
    const int b0   = (sbx & 3) * BPW;
    const float theta = thresholds[post];

    float dly[EPT], wgt[EPT];
#pragma unroll
    for (int j = 0; j < EPT; ++j) {
        int pre = tid * EPT + j;
        dly[j] = delays[pre * POST + post];
        wgt[j] = weights[pre * POST + post];
    }

    // zero paired counts once (later batches re-zero in the scatter slot)
    s_raw[tid] = 0;
    __syncthreads();

    for (int bi = 0; bi < BPW; ++bi) {
        const int b = b0 + bi;

        // ---- times; hist of t<TCUT into s_raw (paired); min of the rest ----
        float4 sp = *reinterpret_cast<const float4*>(spikes + b * PRE + tid * EPT);
        float tv[EPT] = {sp.x + dly[0], sp.y + dly[1], sp.z + dly[2], sp.w + dly[3]};
        int bkt[EPT], rnk[EPT];
        float mloc = INFINITY;
#pragma unroll
        for (int j = 0; j < EPT; ++j) {
            int k = (int)(tv[j] * BSCALE1);
            bkt[j] = k;
            if (k < NB) rnk[j] = hist_add(s_raw, k);
            else        mloc = fminf(mloc, tv[j]);
        }
        mloc = wave_min_f32(mloc);
        __syncthreads();                                   // B1: counts final

        if (lane == 0) s_red[wid] = mloc;                  // written post-B1,
                                                           // read post-B2
        const int N_low = scan_counts(s_raw, s_pck, lane, wid);
        __syncthreads();                                   // B2: pck+s_red visible

        const float minExcl = fminf(fminf(s_red[0], s_red[1]),
                                    fminf(s_red[2], s_red[3]));
        // ---- scatter included; pad holes; wave1 zeroes s_raw ----
#pragma unroll
        for (int j = 0; j < EPT; ++j) {
            if (bkt[j] < NB) {
                int pos = (s_pck[bkt[j]] >> 12) + rnk[j];
                s_t[pos] = tv[j];
                s_w[pos] = wgt[j];
            }
        }
        if (wid == 1)   // all s_raw reads completed at B2
            reinterpret_cast<int4*>(s_raw)[lane] = make_int4(0, 0, 0, 0);
        const int roundup = (N_low + CHUNK - 1) & ~(CHUNK - 1);
        int h = N_low + tid;
        if (h < roundup) { s_t[h] = minExcl; s_w[h] = 0.f; }
        __syncthreads();                                   // B3: scatter+zero visible

        // ---- epoch 0 (typically one chunk, exact early exit) ----
        float cumW = 0.f, cumWT = 0.f, mAll = INFINITY;
        bool done = run_epoch(s_t, s_w, s_pck, s_fw, s_fwt, s_red,
                              0, roundup, 0, N_low, 0.f, 0, minExcl, theta, BSCALE1,
                              tid, lane, wid, cumW, cumWT, mAll);

        // ---- rare fallback: full-range re-solve from scratch (exact) ----
        if (!done) {
            // s_raw is zeroed (B3); s_pck dead. Re-bucket ALL events over [0,2).
            int bk2[EPT], rk2[EPT];
#pragma unroll
            for (int j = 0; j < EPT; ++j) {
                int k = (int)(tv[j] * BSCALE2); k = k < NB - 1 ? k : NB - 1;
                bk2[j] = k;
                rk2[j] = hist_add(s_raw, k);
            }
            __syncthreads();                               // counts final
            (void)scan_counts(s_raw, s_pck, lane, wid);
            __syncthreads();                               // pck visible
#pragma unroll
            for (int j = 0; j < EPT; ++j) {
                int pos = (s_pck[bk2[j]] >> 12) + rk2[j];
                s_t[pos] = tv[j];
                s_w[pos] = wgt[j];
            }
            if (wid == 1)   // re-zero for next batch
                reinterpret_cast<int4*>(s_raw)[lane] = make_int4(0, 0, 0, 0);
            __syncthreads();                               // scatter+zero visible
            cumW = 0.f; cumWT = 0.f; mAll = INFINITY;      // fresh full solve
            run_epoch(s_t, s_w, s_pck, s_fw, s_fwt, s_red,
                      0, PRE, 0, PRE, 0.f, 0, INFINITY, theta, BSCALE2,
                      tid, lane, wid, cumW, cumWT, mAll);
        }

        if (tid == 0) out[b * POST + post] = mAll;
        // No trailing barrier: next batch's hist atomics target s_raw, whose
        // zeroing was barrier-ordered before any post-barrier reader, and the
        // epoch reads only s_t/s_w/s_pck (rewritten next batch post-B2/B3).
    }
}

extern "C" void kernel_launch(void* const* d_in, const int* in_sizes, int n_in,
                              void* d_out, int out_size, void* d_ws, size_t ws_size,
                              hipStream_t stream) {
    const float* spikes     = (const float*)d_in[0]; // [32,1024]
    const float* weights    = (const float*)d_in[1]; // [1024,1024]
    const float* delays     = (const float*)d_in[2]; // [1024,1024]
    const float* thresholds = (const float*)d_in[3]; // [1024]
    float* outp = (float*)d_out;                     // [32,1024]

    dim3 grid(POST * (B_TOT / BPW)); // 4096 workgroups
    dim3 block(TPB);
    equaltime_kernel<<<grid, block, 0, stream>>>(spikes, weights, delays, thresholds, outp);
}

// Round 12
// 140.926 us; speedup vs baseline: 1.5267x; 1.0433x over previous
//
#include <hip/hip_runtime.h>
#include <math.h>

// EqualtimeLayer: per (b,post): sort 1024 events by t = spike[b][pre]+delay[pre][post],
// prefix-sum (w, w*t) in sorted order, candidate tmp_k=(theta+cumwt)/cumw valid iff
// cumw>0 && tmp>=t_k && (k==last || tmp<=t_{k+1}); output = min valid tmp.
//
// R12 = exact R8 skeleton (proven 79us, spill-free) + two local edits:
//  1. conflict-free count scan: int4 reads at [lane] and [lane+64] (contiguous
//     b128; R8's [2*lane] stride-32B reads were 8-way conflicted) with a
//     split-halves prefix (half-2 offset by half-1 total). Zeroing likewise.
//  2. BPW 8->4 (8192 WGs) to smooth early-exit variance / drain tail.
// Only events t < 0.625 (~20%) are bucketed/sorted (512 buckets); the rest
// contribute their exact min time (epoch-0 boundary). Crossing t*~0.49 =>
// epoch 0 is one 256-chunk with exact early exit. Fallback = R8's tail-only
// re-sort reusing bkt/rnk registers (the no-spill variant).

#define B_TOT 32
#define PRE 1024
#define POST 1024
#define NB 512
#define TPB 256
#define EPT 4
#define BPW 4
#define CHUNK 256
#define TCUTF 0.625f
#define BSCALE 819.2f      // 512 buckets over [0, 0.625)

// ---- DPP helpers (gfx9 encodings) ----
template<int CTRL, int MASK>
__device__ __forceinline__ int dpp_add_i32(int v) {
    return v + __builtin_amdgcn_update_dpp(0, v, CTRL, MASK, 0xf, true);
}
template<int CTRL, int MASK>
__device__ __forceinline__ float dpp_add_f32(float v) {
    int t = __builtin_amdgcn_update_dpp(0, __float_as_int(v), CTRL, MASK, 0xf, true);
    return v + __int_as_float(t);
}
template<int CTRL>
__device__ __forceinline__ float dpp_min_f32(float v) {
    int t = __builtin_amdgcn_update_dpp(__float_as_int(v), __float_as_int(v), CTRL, 0xf, 0xf, false);
    return fminf(v, __int_as_float(t));
}
__device__ __forceinline__ int wave_iscan_i32(int v) {
    v = dpp_add_i32<0x111, 0xf>(v);
    v = dpp_add_i32<0x112, 0xf>(v);
    v = dpp_add_i32<0x114, 0xf>(v);
    v = dpp_add_i32<0x118, 0xf>(v);
    v = dpp_add_i32<0x142, 0xa>(v);
    v = dpp_add_i32<0x143, 0xc>(v);
    return v;
}
__device__ __forceinline__ float wave_iscan_f32(float v) {
    v = dpp_add_f32<0x111, 0xf>(v);
    v = dpp_add_f32<0x112, 0xf>(v);
    v = dpp_add_f32<0x114, 0xf>(v);
    v = dpp_add_f32<0x118, 0xf>(v);
    v = dpp_add_f32<0x142, 0xa>(v);
    v = dpp_add_f32<0x143, 0xc>(v);
    return v;
}
__device__ __forceinline__ float wave_min_f32(float v) {
    v = fminf(v, __shfl_down(v, 32));
    v = fminf(v, __shfl_down(v, 16));
    v = dpp_min_f32<0x140>(v);
    v = dpp_min_f32<0x141>(v);
    v = dpp_min_f32<0x4E>(v);
    v = dpp_min_f32<0xB1>(v);
    return v;
}
__device__ __forceinline__ int clampb(int k) {
    return k < 0 ? 0 : (k > NB - 1 ? NB - 1 : k);
}

// Redundant (every wave identical) exclusive scan of NB 32-bit counts.
// Conflict-free reads: int4 at [lane] (buckets 4L..4L+3) and [lane+64]
// (buckets 256+4L..). Split-halves prefix: half-2 offset by half-1 total.
// Wave 0 writes packed (off<<12|cnt) into pck. Returns total (uniform).
__device__ __forceinline__ int scan_counts(const int* raw, int* pck, int lane, int wid) {
    int4 a = reinterpret_cast<const int4*>(raw)[lane];
    int4 bq = reinterpret_cast<const int4*>(raw)[lane + 64];
    int c1[4] = {a.x, a.y, a.z, a.w};
    int c2[4] = {bq.x, bq.y, bq.z, bq.w};
    int ls1[4], ls2[4];
    int s1 = 0, s2 = 0;
#pragma unroll
    for (int j = 0; j < 4; ++j) { s1 += c1[j]; ls1[j] = s1; }
#pragma unroll
    for (int j = 0; j < 4; ++j) { s2 += c2[j]; ls2[j] = s2; }
    int x1 = wave_iscan_i32(s1);
    int x2 = wave_iscan_i32(s2);
    int tot1 = __builtin_amdgcn_readlane(x1, 63);
    int e1 = x1 - s1;
    int e2 = tot1 + x2 - s2;
    if (wid == 0) {
        int o1[4], o2[4];
#pragma unroll
        for (int j = 0; j < 4; ++j) {
            o1[j] = ((e1 + ls1[j] - c1[j]) << 12) | c1[j];
            o2[j] = ((e2 + ls2[j] - c2[j]) << 12) | c2[j];
        }
        reinterpret_cast<int4*>(pck)[lane]      = make_int4(o1[0], o1[1], o1[2], o1[3]);
        reinterpret_cast<int4*>(pck)[lane + 64] = make_int4(o2[0], o2[1], o2[2], o2[3]);
    }
    return tot1 + __builtin_amdgcn_readlane(x2, 63);
}

// Block-cooperative chunked solve (R8-proven, unchanged).
__device__ __forceinline__ bool run_epoch(
    float* s_t, float* s_w, const int* pck, float* s_fw, float* s_fwt, float* s_red,
    int cStart, int cEnd, int posLo, int posValidEnd,
    float t0f, int baseOff, float tEnd, float theta,
    int tid, int lane, int wid, float& cumW, float& cumWT, float& mAll)
{
    for (int c0 = cStart; c0 < cEnd; c0 += CHUNK) {
        const int next = c0 + CHUNK;
        const int p = c0 + tid;
        const bool valid = (p >= posLo);

        float e_t = s_t[p], e_w = s_w[p];
        int np = -1;
        if (valid) {
            int k = clampb((int)((e_t - t0f) * BSCALE));
            int pk = pck[k];
            int bas = (pk >> 12) + baseOff, cn = pk & 0xfff;
            if (bas >= c0 && cn > 1) {
                int r = 0;
                for (int q = bas; q < bas + cn; ++q) {
                    float tq = s_t[q];
                    r += ((tq < e_t) || (tq == e_t && q < p)) ? 1 : 0;
                }
                int tgt = bas + r;
                if (tgt != p) np = tgt;
            }
        }
        int np2 = -1; float e2t = 0.f, e2w = 0.f;
        if (tid < 64) {
            int p2 = next + tid;
            if (p2 < cEnd && p2 >= posLo) {
                e2t = s_t[p2]; e2w = s_w[p2];
                int k = clampb((int)((e2t - t0f) * BSCALE));
                int pk = pck[k];
                int bas = (pk >> 12) + baseOff, cn = pk & 0xfff;
                if (bas >= c0 && bas < next && cn > 1) {
                    int r = 0;
                    for (int q = bas; q < bas + cn; ++q) {
                        float tq = s_t[q];
                        r += ((tq < e2t) || (tq == e2t && q < p2)) ? 1 : 0;
                    }
                    int tgt = bas + r;
                    if (tgt != p2) np2 = tgt;
                }
            }
        }
        __syncthreads();                                   // gathers done
        if (np  >= 0) { s_t[np]  = e_t;  s_w[np]  = e_w; }
        if (np2 >= 0) { s_t[np2] = e2t; s_w[np2] = e2w; }
        __syncthreads();                                   // fixup visible

        float t_next = tEnd;
        if (next < cEnd) {
            float tx = s_t[next];
            int k = clampb((int)((tx - t0f) * BSCALE));
            int pk = pck[k];
            int bas = (pk >> 12) + baseOff, cn = pk & 0xfff;
            t_next = tx;
            if (bas >= next) {
                for (int q = bas; q < bas + cn; ++q) t_next = fminf(t_next, s_t[q]);
            }
        }

        float t_p = s_t[p];
        float w_p = valid ? s_w[p] : 0.f;
        float aw = w_p, awt = w_p * t_p;
        float xw  = wave_iscan_f32(aw);
        float xwt = wave_iscan_f32(awt);
        if (lane == 63) { s_fw[wid] = xw; s_fwt[wid] = xwt; }
        float tn = (p == PRE - 1) ? INFINITY
                 : (tid == TPB - 1) ? t_next : s_t[p + 1];
        __syncthreads();                                   // partials visible
        float W = cumW, WT = cumWT;
        for (int k2 = 0; k2 < wid; ++k2) { W += s_fw[k2]; WT += s_fwt[k2]; }
        W += xw; WT += xwt;
        cumW  += s_fw[0] + s_fw[1] + s_fw[2] + s_fw[3];
        cumWT += s_fwt[0] + s_fwt[1] + s_fwt[2] + s_fwt[3];

        float mc = INFINITY;
        if (valid && p < posValidEnd && W > 0.f) {
            float tmp = (theta + WT) * __builtin_amdgcn_rcpf(W);
            if (tmp >= t_p && tmp <= tn) mc = tmp;
        }
        mc = wave_min_f32(mc);
        if (lane == 0) s_red[wid] = mc;
        __syncthreads();                                   // mins visible
        mAll = fminf(mAll,
               fminf(fminf(s_red[0], s_red[1]), fminf(s_red[2], s_red[3])));
        if (mAll <= t_next) return true;
    }
    return false;
}

__global__ __launch_bounds__(TPB, 8) void equaltime_kernel(
    const float* __restrict__ spikes,     // [B][PRE]
    const float* __restrict__ weights,    // [PRE][POST]
    const float* __restrict__ delays,     // [PRE][POST]
    const float* __restrict__ thresholds, // [POST]
    float* __restrict__ out)              // [B][POST]
{
    __shared__ __align__(16) float s_t[PRE];   // 4 KB
    __shared__ __align__(16) float s_w[PRE];   // 4 KB
    __shared__ __align__(16) int   s_raw[NB];  // 2 KB raw counts (hist target)
    __shared__ __align__(16) int   s_pck[NB];  // 2 KB packed (off<<12|cnt)
    __shared__ float s_fw[4], s_fwt[4];
    __shared__ float s_red[4];

    const int tid  = threadIdx.x;
    const int lane = tid & 63;
    const int wid  = tid >> 6;

    // XCD-contiguous swizzle for weight/delay L2 locality
    const int bx   = blockIdx.x;
    const int sbx  = (bx & 7) * 1024 + (bx >> 3);
    const int post = sbx >> 3;            // 8 WGs per post
    const int b0   = (sbx & 7) * BPW;
    const float theta = thresholds[post];

    float dly[EPT], wgt[EPT];
#pragma unroll
    for (int j = 0; j < EPT; ++j) {
        int pre = tid * EPT + j;
        dly[j] = delays[pre * POST + post];
        wgt[j] = weights[pre * POST + post];
    }

    // zero raw counts once (subsequent batches re-zero in the scatter slot)
    reinterpret_cast<int2*>(s_raw)[tid] = make_int2(0, 0);
    __syncthreads();

    for (int bi = 0; bi < BPW; ++bi) {
        const int b = b0 + bi;

        // ---- times; hist of t<TCUT into s_raw; min of the rest ----
        float4 sp = *reinterpret_cast<const float4*>(spikes + b * PRE + tid * EPT);
        float tv[EPT] = {sp.x + dly[0], sp.y + dly[1], sp.z + dly[2], sp.w + dly[3]};
        int bkt[EPT], rnk[EPT];
        float mloc = INFINITY;
#pragma unroll
        for (int j = 0; j < EPT; ++j) {
            int k = (int)(tv[j] * BSCALE);
            bkt[j] = k;
            if (k < NB) rnk[j] = atomicAdd(&s_raw[k], 1);
            else        mloc = fminf(mloc, tv[j]);
        }
        mloc = wave_min_f32(mloc);
        __syncthreads();                                   // B1: counts final

        if (lane == 0) s_red[wid] = mloc;                  // post-B1 write,
                                                           // post-B2 read
        const int N_low = scan_counts(s_raw, s_pck, lane, wid); // reads raw only
        __syncthreads();                                   // B2: pck + s_red visible

        const float minExcl = fminf(fminf(s_red[0], s_red[1]),
                                    fminf(s_red[2], s_red[3]));
        // ---- scatter included (reads s_pck); pad holes; wave1 zeroes s_raw ----
#pragma unroll
        for (int j = 0; j < EPT; ++j) {
            if (bkt[j] < NB) {
                int pos = (s_pck[bkt[j]] >> 12) + rnk[j];
                s_t[pos] = tv[j];
                s_w[pos] = wgt[j];
            }
        }
        if (wid == 1) {   // all s_raw reads completed at B2; contiguous writes
            reinterpret_cast<int4*>(s_raw)[lane]      = make_int4(0, 0, 0, 0);
            reinterpret_cast<int4*>(s_raw)[lane + 64] = make_int4(0, 0, 0, 0);
        }
        const int roundup = (N_low + CHUNK - 1) & ~(CHUNK - 1);
        int h = N_low + tid;
        if (h < roundup) { s_t[h] = minExcl; s_w[h] = 0.f; }
        __syncthreads();                                   // B3: scatter+zero visible

        // ---- epoch 0 (typically one chunk, exact early exit) ----
        float cumW = 0.f, cumWT = 0.f, mAll = INFINITY;
        bool done = run_epoch(s_t, s_w, s_pck, s_fw, s_fwt, s_red,
                              0, roundup, 0, N_low, 0.f, 0, minExcl, theta,
                              tid, lane, wid, cumW, cumWT, mAll);

        // ---- rare exact fallback: sort & process the excluded tail ----
        if (!done && N_low < PRE) {
            // s_raw is zeroed; s_pck is dead (epoch 0 finished). Reuse bkt/rnk.
#pragma unroll
            for (int j = 0; j < EPT; ++j) {
                if (bkt[j] >= NB) {
                    int k2 = clampb((int)((tv[j] - TCUTF) * BSCALE));
                    bkt[j] = NB + k2;          // remember tail bucket
                    rnk[j] = atomicAdd(&s_raw[k2], 1);
                }
            }
            __syncthreads();                               // counts final
            (void)scan_counts(s_raw, s_pck, lane, wid);    // wave 0 packs
            __syncthreads();                               // pck visible
#pragma unroll
            for (int j = 0; j < EPT; ++j) {
                if (bkt[j] >= NB) {
                    int k2 = bkt[j] - NB;
                    int pos = N_low + (s_pck[k2] >> 12) + rnk[j];
                    s_t[pos] = tv[j];
                    s_w[pos] = wgt[j];
                }
            }
            if (wid == 1) {   // re-zero raw for the next batch
                reinterpret_cast<int4*>(s_raw)[lane]      = make_int4(0, 0, 0, 0);
                reinterpret_cast<int4*>(s_raw)[lane + 64] = make_int4(0, 0, 0, 0);
            }
            __syncthreads();                               // scatter+zero visible
            run_epoch(s_t, s_w, s_pck, s_fw, s_fwt, s_red,
                      N_low & ~(CHUNK - 1), PRE, N_low, PRE,
                      TCUTF, N_low, INFINITY, theta,
                      tid, lane, wid, cumW, cumWT, mAll);
        }

        if (tid == 0) out[b * POST + post] = mAll;
        // No trailing barrier: next batch's hist atomics target s_raw, whose
        // zeroing was barrier-ordered before any post-barrier reader.
    }
}

extern "C" void kernel_launch(void* const* d_in, const int* in_sizes, int n_in,
                              void* d_out, int out_size, void* d_ws, size_t ws_size,
                              hipStream_t stream) {
    const float* spikes     = (const float*)d_in[0]; // [32,1024]
    const float* weights    = (const float*)d_in[1]; // [1024,1024]
    const float* delays     = (const float*)d_in[2]; // [1024,1024]
    const float* thresholds = (const float*)d_in[3]; // [1024]
    float* outp = (float*)d_out;                     // [32,1024]

    dim3 grid(POST * (B_TOT / BPW)); // 8192 workgroups
    dim3 block(TPB);
    equaltime_kernel<<<grid, block, 0, stream>>>(spikes, weights, delays, thresholds, outp);
}

// Round 13
// 132.012 us; speedup vs baseline: 1.6298x; 1.0675x over previous
//
#include <hip/hip_runtime.h>
#include <math.h>

// EqualtimeLayer: per (b,post): sort 1024 events by t = spike[b][pre]+delay[pre][post],
// prefix-sum (w, w*t) in sorted order, candidate tmp_k=(theta+cumwt)/cumw valid iff
// cumw>0 && tmp>=t_k && (k==last || tmp<=t_{k+1}); output = min valid tmp.
//
// R13 = R8 skeleton (BPW=8, proven 79us, spill-free) + R12's conflict-free
// count scan (int4 at [lane]/[lane+64], split-halves prefix; measured
// 4.18e6 -> 2.06e6 conflict cycles). R12's BPW=4 reverted (doubled the
// uncoalesced column-load prologue cost: 79 -> 89us).
// Only events t < 0.625 (~20%) are bucketed/sorted (512 buckets); the rest
// contribute their exact min time (epoch-0 boundary). Crossing t*~0.49 =>
// epoch 0 is one 256-chunk with exact early exit. Fallback = tail-only
// re-sort reusing bkt/rnk registers (no extra live state -> no spill).

#define B_TOT 32
#define PRE 1024
#define POST 1024
#define NB 512
#define TPB 256
#define EPT 4
#define BPW 8
#define CHUNK 256
#define TCUTF 0.625f
#define BSCALE 819.2f      // 512 buckets over [0, 0.625)

// ---- DPP helpers (gfx9 encodings) ----
template<int CTRL, int MASK>
__device__ __forceinline__ int dpp_add_i32(int v) {
    return v + __builtin_amdgcn_update_dpp(0, v, CTRL, MASK, 0xf, true);
}
template<int CTRL, int MASK>
__device__ __forceinline__ float dpp_add_f32(float v) {
    int t = __builtin_amdgcn_update_dpp(0, __float_as_int(v), CTRL, MASK, 0xf, true);
    return v + __int_as_float(t);
}
template<int CTRL>
__device__ __forceinline__ float dpp_min_f32(float v) {
    int t = __builtin_amdgcn_update_dpp(__float_as_int(v), __float_as_int(v), CTRL, 0xf, 0xf, false);
    return fminf(v, __int_as_float(t));
}
__device__ __forceinline__ int wave_iscan_i32(int v) {
    v = dpp_add_i32<0x111, 0xf>(v);
    v = dpp_add_i32<0x112, 0xf>(v);
    v = dpp_add_i32<0x114, 0xf>(v);
    v = dpp_add_i32<0x118, 0xf>(v);
    v = dpp_add_i32<0x142, 0xa>(v);
    v = dpp_add_i32<0x143, 0xc>(v);
    return v;
}
__device__ __forceinline__ float wave_iscan_f32(float v) {
    v = dpp_add_f32<0x111, 0xf>(v);
    v = dpp_add_f32<0x112, 0xf>(v);
    v = dpp_add_f32<0x114, 0xf>(v);
    v = dpp_add_f32<0x118, 0xf>(v);
    v = dpp_add_f32<0x142, 0xa>(v);
    v = dpp_add_f32<0x143, 0xc>(v);
    return v;
}
__device__ __forceinline__ float wave_min_f32(float v) {
    v = fminf(v, __shfl_down(v, 32));
    v = fminf(v, __shfl_down(v, 16));
    v = dpp_min_f32<0x140>(v);
    v = dpp_min_f32<0x141>(v);
    v = dpp_min_f32<0x4E>(v);
    v = dpp_min_f32<0xB1>(v);
    return v;
}
__device__ __forceinline__ int clampb(int k) {
    return k < 0 ? 0 : (k > NB - 1 ? NB - 1 : k);
}

// Redundant (every wave identical) exclusive scan of NB 32-bit counts.
// Conflict-free reads: int4 at [lane] (buckets 4L..4L+3) and [lane+64]
// (buckets 256+4L..). Split-halves prefix: half-2 offset by half-1 total.
// Wave 0 writes packed (off<<12|cnt) into pck. Returns total (uniform).
__device__ __forceinline__ int scan_counts(const int* raw, int* pck, int lane, int wid) {
    int4 a = reinterpret_cast<const int4*>(raw)[lane];
    int4 bq = reinterpret_cast<const int4*>(raw)[lane + 64];
    int c1[4] = {a.x, a.y, a.z, a.w};
    int c2[4] = {bq.x, bq.y, bq.z, bq.w};
    int ls1[4], ls2[4];
    int s1 = 0, s2 = 0;
#pragma unroll
    for (int j = 0; j < 4; ++j) { s1 += c1[j]; ls1[j] = s1; }
#pragma unroll
    for (int j = 0; j < 4; ++j) { s2 += c2[j]; ls2[j] = s2; }
    int x1 = wave_iscan_i32(s1);
    int x2 = wave_iscan_i32(s2);
    int tot1 = __builtin_amdgcn_readlane(x1, 63);
    int e1 = x1 - s1;
    int e2 = tot1 + x2 - s2;
    if (wid == 0) {
        int o1[4], o2[4];
#pragma unroll
        for (int j = 0; j < 4; ++j) {
            o1[j] = ((e1 + ls1[j] - c1[j]) << 12) | c1[j];
            o2[j] = ((e2 + ls2[j] - c2[j]) << 12) | c2[j];
        }
        reinterpret_cast<int4*>(pck)[lane]      = make_int4(o1[0], o1[1], o1[2], o1[3]);
        reinterpret_cast<int4*>(pck)[lane + 64] = make_int4(o2[0], o2[1], o2[2], o2[3]);
    }
    return tot1 + __builtin_amdgcn_readlane(x2, 63);
}

// Block-cooperative chunked solve (R8-proven, unchanged).
__device__ __forceinline__ bool run_epoch(
    float* s_t, float* s_w, const int* pck, float* s_fw, float* s_fwt, float* s_red,
    int cStart, int cEnd, int posLo, int posValidEnd,
    float t0f, int baseOff, float tEnd, float theta,
    int tid, int lane, int wid, float& cumW, float& cumWT, float& mAll)
{
    for (int c0 = cStart; c0 < cEnd; c0 += CHUNK) {
        const int next = c0 + CHUNK;
        const int p = c0 + tid;
        const bool valid = (p >= posLo);

        float e_t = s_t[p], e_w = s_w[p];
        int np = -1;
        if (valid) {
            int k = clampb((int)((e_t - t0f) * BSCALE));
            int pk = pck[k];
            int bas = (pk >> 12) + baseOff, cn = pk & 0xfff;
            if (bas >= c0 && cn > 1) {
                int r = 0;
                for (int q = bas; q < bas + cn; ++q) {
                    float tq = s_t[q];
                    r += ((tq < e_t) || (tq == e_t && q < p)) ? 1 : 0;
                }
                int tgt = bas + r;
                if (tgt != p) np = tgt;
            }
        }
        int np2 = -1; float e2t = 0.f, e2w = 0.f;
        if (tid < 64) {
            int p2 = next + tid;
            if (p2 < cEnd && p2 >= posLo) {
                e2t = s_t[p2]; e2w = s_w[p2];
                int k = clampb((int)((e2t - t0f) * BSCALE));
                int pk = pck[k];
                int bas = (pk >> 12) + baseOff, cn = pk & 0xfff;
                if (bas >= c0 && bas < next && cn > 1) {
                    int r = 0;
                    for (int q = bas; q < bas + cn; ++q) {
                        float tq = s_t[q];
                        r += ((tq < e2t) || (tq == e2t && q < p2)) ? 1 : 0;
                    }
                    int tgt = bas + r;
                    if (tgt != p2) np2 = tgt;
                }
            }
        }
        __syncthreads();                                   // gathers done
        if (np  >= 0) { s_t[np]  = e_t;  s_w[np]  = e_w; }
        if (np2 >= 0) { s_t[np2] = e2t; s_w[np2] = e2w; }
        __syncthreads();                                   // fixup visible

        float t_next = tEnd;
        if (next < cEnd) {
            float tx = s_t[next];
            int k = clampb((int)((tx - t0f) * BSCALE));
            int pk = pck[k];
            int bas = (pk >> 12) + baseOff, cn = pk & 0xfff;
            t_next = tx;
            if (bas >= next) {
                for (int q = bas; q < bas + cn; ++q) t_next = fminf(t_next, s_t[q]);
            }
        }

        float t_p = s_t[p];
        float w_p = valid ? s_w[p] : 0.f;
        float aw = w_p, awt = w_p * t_p;
        float xw  = wave_iscan_f32(aw);
        float xwt = wave_iscan_f32(awt);
        if (lane == 63) { s_fw[wid] = xw; s_fwt[wid] = xwt; }
        float tn = (p == PRE - 1) ? INFINITY
                 : (tid == TPB - 1) ? t_next : s_t[p + 1];
        __syncthreads();                                   // partials visible
        float W = cumW, WT = cumWT;
        for (int k2 = 0; k2 < wid; ++k2) { W += s_fw[k2]; WT += s_fwt[k2]; }
        W += xw; WT += xwt;
        cumW  += s_fw[0] + s_fw[1] + s_fw[2] + s_fw[3];
        cumWT += s_fwt[0] + s_fwt[1] + s_fwt[2] + s_fwt[3];

        float mc = INFINITY;
        if (valid && p < posValidEnd && W > 0.f) {
            float tmp = (theta + WT) * __builtin_amdgcn_rcpf(W);
            if (tmp >= t_p && tmp <= tn) mc = tmp;
        }
        mc = wave_min_f32(mc);
        if (lane == 0) s_red[wid] = mc;
        __syncthreads();                                   // mins visible
        mAll = fminf(mAll,
               fminf(fminf(s_red[0], s_red[1]), fminf(s_red[2], s_red[3])));
        if (mAll <= t_next) return true;
    }
    return false;
}

__global__ __launch_bounds__(TPB, 8) void equaltime_kernel(
    const float* __restrict__ spikes,     // [B][PRE]
    const float* __restrict__ weights,    // [PRE][POST]
    const float* __restrict__ delays,     // [PRE][POST]
    const float* __restrict__ thresholds, // [POST]
    float* __restrict__ out)              // [B][POST]
{
    __shared__ __align__(16) float s_t[PRE];   // 4 KB
    __shared__ __align__(16) float s_w[PRE];   // 4 KB
    __shared__ __align__(16) int   s_raw[NB];  // 2 KB raw counts (hist target)
    __shared__ __align__(16) int   s_pck[NB];  // 2 KB packed (off<<12|cnt)
    __shared__ float s_fw[4], s_fwt[4];
    __shared__ float s_red[4];

    const int tid  = threadIdx.x;
    const int lane = tid & 63;
    const int wid  = tid >> 6;

    // XCD-contiguous swizzle for weight/delay L2 locality
    const int bx   = blockIdx.x;
    const int sbx  = (bx & 7) * 512 + (bx >> 3);
    const int post = sbx >> 2;            // 4 WGs per post
    const int b0   = (sbx & 3) * BPW;
    const float theta = thresholds[post];

    float dly[EPT], wgt[EPT];
#pragma unroll
    for (int j = 0; j < EPT; ++j) {
        int pre = tid * EPT + j;
        dly[j] = delays[pre * POST + post];
        wgt[j] = weights[pre * POST + post];
    }

    // zero raw counts once (subsequent batches re-zero in the scatter slot)
    reinterpret_cast<int2*>(s_raw)[tid] = make_int2(0, 0);
    __syncthreads();

    for (int bi = 0; bi < BPW; ++bi) {
        const int b = b0 + bi;

        // ---- times; hist of t<TCUT into s_raw; min of the rest ----
        float4 sp = *reinterpret_cast<const float4*>(spikes + b * PRE + tid * EPT);
        float tv[EPT] = {sp.x + dly[0], sp.y + dly[1], sp.z + dly[2], sp.w + dly[3]};
        int bkt[EPT], rnk[EPT];
        float mloc = INFINITY;
#pragma unroll
        for (int j = 0; j < EPT; ++j) {
            int k = (int)(tv[j] * BSCALE);
            bkt[j] = k;
            if (k < NB) rnk[j] = atomicAdd(&s_raw[k], 1);
            else        mloc = fminf(mloc, tv[j]);
        }
        mloc = wave_min_f32(mloc);
        __syncthreads();                                   // B1: counts final

        if (lane == 0) s_red[wid] = mloc;                  // post-B1 write,
                                                           // post-B2 read
        const int N_low = scan_counts(s_raw, s_pck, lane, wid); // reads raw only
        __syncthreads();                                   // B2: pck + s_red visible

        const float minExcl = fminf(fminf(s_red[0], s_red[1]),
                                    fminf(s_red[2], s_red[3]));
        // ---- scatter included (reads s_pck); pad holes; wave1 zeroes s_raw ----
#pragma unroll
        for (int j = 0; j < EPT; ++j) {
            if (bkt[j] < NB) {
                int pos = (s_pck[bkt[j]] >> 12) + rnk[j];
                s_t[pos] = tv[j];
                s_w[pos] = wgt[j];
            }
        }
        if (wid == 1) {   // all s_raw reads completed at B2; contiguous writes
            reinterpret_cast<int4*>(s_raw)[lane]      = make_int4(0, 0, 0, 0);
            reinterpret_cast<int4*>(s_raw)[lane + 64] = make_int4(0, 0, 0, 0);
        }
        const int roundup = (N_low + CHUNK - 1) & ~(CHUNK - 1);
        int h = N_low + tid;
        if (h < roundup) { s_t[h] = minExcl; s_w[h] = 0.f; }
        __syncthreads();                                   // B3: scatter+zero visible

        // ---- epoch 0 (typically one chunk, exact early exit) ----
        float cumW = 0.f, cumWT = 0.f, mAll = INFINITY;
        bool done = run_epoch(s_t, s_w, s_pck, s_fw, s_fwt, s_red,
                              0, roundup, 0, N_low, 0.f, 0, minExcl, theta,
                              tid, lane, wid, cumW, cumWT, mAll);

        // ---- rare exact fallback: sort & process the excluded tail ----
        if (!done && N_low < PRE) {
            // s_raw is zeroed; s_pck is dead (epoch 0 finished). Reuse bkt/rnk.
#pragma unroll
            for (int j = 0; j < EPT; ++j) {
                if (bkt[j] >= NB) {
                    int k2 = clampb((int)((tv[j] - TCUTF) * BSCALE));
                    bkt[j] = NB + k2;          // remember tail bucket
                    rnk[j] = atomicAdd(&s_raw[k2], 1);
                }
            }
            __syncthreads();                               // counts final
            (void)scan_counts(s_raw, s_pck, lane, wid);    // wave 0 packs
            __syncthreads();                               // pck visible
#pragma unroll
            for (int j = 0; j < EPT; ++j) {
                if (bkt[j] >= NB) {
                    int k2 = bkt[j] - NB;
                    int pos = N_low + (s_pck[k2] >> 12) + rnk[j];
                    s_t[pos] = tv[j];
                    s_w[pos] = wgt[j];
                }
            }
            if (wid == 1) {   // re-zero raw for the next batch
                reinterpret_cast<int4*>(s_raw)[lane]      = make_int4(0, 0, 0, 0);
                reinterpret_cast<int4*>(s_raw)[lane + 64] = make_int4(0, 0, 0, 0);
            }
            __syncthreads();                               // scatter+zero visible
            run_epoch(s_t, s_w, s_pck, s_fw, s_fwt, s_red,
                      N_low & ~(CHUNK - 1), PRE, N_low, PRE,
                      TCUTF, N_low, INFINITY, theta,
                      tid, lane, wid, cumW, cumWT, mAll);
        }

        if (tid == 0) out[b * POST + post] = mAll;
        // No trailing barrier: next batch's hist atomics target s_raw, whose
        // zeroing was barrier-ordered before any post-barrier reader.
    }
}

extern "C" void kernel_launch(void* const* d_in, const int* in_sizes, int n_in,
                              void* d_out, int out_size, void* d_ws, size_t ws_size,
                              hipStream_t stream) {
    const float* spikes     = (const float*)d_in[0]; // [32,1024]
    const float* weights    = (const float*)d_in[1]; // [1024,1024]
    const float* delays     = (const float*)d_in[2]; // [1024,1024]
    const float* thresholds = (const float*)d_in[3]; // [1024]
    float* outp = (float*)d_out;                     // [32,1024]

    dim3 grid(POST * (B_TOT / BPW)); // 4096 workgroups
    dim3 block(TPB);
    equaltime_kernel<<<grid, block, 0, stream>>>(spikes, weights, delays, thresholds, outp);
}